// Round 5
// baseline (189.742 us; speedup 1.0000x reference)
//
#include <hip/hip_runtime.h>

#define T_TOTAL 262144
#define NBLOCKS 2048
#define NMIX 64
#define NDIM 16

typedef short bf16x8 __attribute__((ext_vector_type(8)));
typedef unsigned short u16x8 __attribute__((ext_vector_type(8)));
typedef unsigned short u16x4 __attribute__((ext_vector_type(4)));
typedef float f32x4 __attribute__((ext_vector_type(4)));

__device__ __forceinline__ unsigned short f2bf(float f) {
    union { float f; unsigned u; } v; v.f = f;
    unsigned r = v.u + 0x7fff + ((v.u >> 16) & 1);   // RNE
    return (unsigned short)(r >> 16);
}
__device__ __forceinline__ float bf2f(unsigned short s) {
    union { unsigned u; float f; } v; v.u = ((unsigned)s) << 16;
    return v.f;
}

// LDS layout (bytes):
//   L_WH   0      64 rows x 80 B (32 bf16 + pad)         5120
//   L_WL   5120                                           5120
//   L_MUT  10240  16 rows x 144 B (64 bf16 + pad)         2304
//   L_A2   12544  64 f32                                   256
//   L_RED  12800  4 f32 loglike partials                    16
//   L_FLAG 12816  int last-block flag                        4
//   L_DRED 12824  4 doubles (final reduce)                  32
//   L_F    12864  4 waves x (Fh 32x80 | Fl 32x80)        20480
//   L_P    33344  4 waves x 16 rows x 144 B               9216
//   total 42560
#define L_WH   0
#define L_WL   5120
#define L_MUT  10240
#define L_A2   12544
#define L_RED  12800
#define L_FLAG 12816
#define L_DRED 12824
#define L_F    12864
#define L_P    33344

__global__ __launch_bounds__(256, 3) void gmm_main(const float* __restrict__ data,
                                                   const float* __restrict__ wghts,
                                                   const float* __restrict__ means,
                                                   const float* __restrict__ dcovs,
                                                   float* __restrict__ out,
                                                   float* __restrict__ part,
                                                   unsigned* __restrict__ cnt) {
    __shared__ __align__(16) char lds[42560];
    const int tid  = threadIdx.x;
    const int w    = tid >> 6;        // wave id
    const int lane = tid & 63;
    const int gi   = lane & 15;       // fragment row/col index
    const int gq   = lane >> 4;       // fragment quad
    const size_t tblk = (size_t)blockIdx.x * 128;

    // ---- phase A: issue this thread's data loads (overlap with W prep) ----
    const int row = tid >> 1, half = tid & 1;     // local point 0..127, dim-half
    const float4* xp = (const float4*)(data + (tblk + row) * 16 + half * 8);
    float4 xa = xp[0], xb = xp[1];

    // ---- phase B: distributed W/MU/A2 prep: 4 threads per mixture ----
    {
        const int m  = tid >> 2;
        const int ql = tid & 3;       // dim-quarter
        const float LOG2E = 1.4426950408889634f;
        const float LOG2_2PI = 2.6514961294723187f;  // log2(6.283185307)
        const float4 d4 = *(const float4*)(dcovs + m * 16 + ql * 4);
        const float4 m4 = *(const float4*)(means + m * 16 + ql * 4);
        const float wm = wghts[m];
        float dc[4] = {d4.x, d4.y, d4.z, d4.w};
        float mu[4] = {m4.x, m4.y, m4.z, m4.w};
        u16x4 ghv, glv, hhv, hlv;
        float sumlog = 0.0f, qsum = 0.0f;
        unsigned short* mut = (unsigned short*)(lds + L_MUT);
#pragma unroll
        for (int j = 0; j < 4; ++j) {
            float pr = __builtin_amdgcn_rcpf(dc[j]);
            float g = -0.5f * LOG2E * pr;     // coeff of x^2
            float h = LOG2E * pr * mu[j];     // coeff of x
            unsigned short gH = f2bf(g), hH = f2bf(h);
            ghv[j] = gH;  glv[j] = f2bf(g - bf2f(gH));
            hhv[j] = hH;  hlv[j] = f2bf(h - bf2f(hH));
            mut[(ql * 4 + j) * 72 + m] = f2bf(mu[j]);
            sumlog += __builtin_amdgcn_logf(dc[j]);   // log2
            qsum   += pr * mu[j] * mu[j];
        }
        char* wrh = lds + L_WH + m * 80;
        char* wrl = lds + L_WL + m * 80;
        *(u16x4*)(wrh + ql * 8)      = ghv;
        *(u16x4*)(wrh + 32 + ql * 8) = hhv;
        *(u16x4*)(wrl + ql * 8)      = glv;
        *(u16x4*)(wrl + 32 + ql * 8) = hlv;
        sumlog += __shfl_xor(sumlog, 1); sumlog += __shfl_xor(sumlog, 2);
        qsum   += __shfl_xor(qsum, 1);   qsum   += __shfl_xor(qsum, 2);
        if (ql == 0) {
            float log2C = __builtin_amdgcn_logf(wm) - 8.0f * LOG2_2PI - 0.5f * sumlog;
            ((float*)(lds + L_A2))[m] = log2C - 0.5f * LOG2E * qsum;
        }
    }

    // ---- phase C: F staging [x^2(16), x(16)] hi/lo bf16 ----
    {
        int fw = row >> 5, lr = row & 31;     // owning wave region, local row
        float xv[8] = {xa.x, xa.y, xa.z, xa.w, xb.x, xb.y, xb.z, xb.w};
        u16x8 vh2, vl2, vhx, vlx;
#pragma unroll
        for (int d = 0; d < 8; ++d) {
            float q = xv[d] * xv[d];
            unsigned short qh = f2bf(q);
            vh2[d] = qh;               vl2[d] = f2bf(q - bf2f(qh));
            unsigned short xh = f2bf(xv[d]);
            vhx[d] = xh;               vlx[d] = f2bf(xv[d] - bf2f(xh));
        }
        char* fb = lds + L_F + fw * 5120 + lr * 80;
        *(u16x8*)(fb + half * 16)        = vh2;   // k = half*8+d    (x^2 terms)
        *(u16x8*)(fb + 32 + half * 16)   = vhx;   // k = 16+half*8+d (x terms)
        char* fl = fb + 2560;
        *(u16x8*)(fl + half * 16)        = vl2;
        *(u16x8*)(fl + 32 + half * 16)   = vlx;
    }
    __syncthreads();

    // ---- preload B fragments (wave-invariant) ----
    bf16x8 bh[4], bl[4];
    float a2v[4];
#pragma unroll
    for (int c = 0; c < 4; ++c) {
        bh[c] = *(const bf16x8*)(lds + L_WH + (c * 16 + gi) * 80 + gq * 16);
        bl[c] = *(const bf16x8*)(lds + L_WL + (c * 16 + gi) * 80 + gq * 16);
        a2v[c] = ((const float*)(lds + L_A2))[c * 16 + gi];
    }
    bf16x8 mf0 = *(const bf16x8*)(lds + L_MUT + gi * 144 + gq * 16);
    bf16x8 mf1 = *(const bf16x8*)(lds + L_MUT + gi * 144 + 64 + gq * 16);

    const char* fbase = lds + L_F + w * 5120;
    char* pbase = lds + L_P + w * 2304;
    float ll_acc = 0.0f;

#pragma unroll
    for (int rt = 0; rt < 2; ++rt) {
        bf16x8 ah = *(const bf16x8*)(fbase + (rt * 16 + gi) * 80 + gq * 16);
        bf16x8 al = *(const bf16x8*)(fbase + 2560 + (rt * 16 + gi) * 80 + gq * 16);

        // S = fl*wh + fh*wl + fh*wh  (hi/lo split), 4 column tiles of 16 m
        f32x4 pacc[4];
#pragma unroll
        for (int c = 0; c < 4; ++c) {
            f32x4 a = {0.0f, 0.0f, 0.0f, 0.0f};
            a = __builtin_amdgcn_mfma_f32_16x16x32_bf16(al, bh[c], a, 0, 0, 0);
            a = __builtin_amdgcn_mfma_f32_16x16x32_bf16(ah, bl[c], a, 0, 0, 0);
            a = __builtin_amdgcn_mfma_f32_16x16x32_bf16(ah, bh[c], a, 0, 0, 0);
            pacc[c] = a;
        }

        // exp2 + row sums (C layout: row = gq*4+reg, col = c*16+gi)
        float p[4][4], prow[4], inv[4];
#pragma unroll
        for (int reg = 0; reg < 4; ++reg) {
#pragma unroll
            for (int c = 0; c < 4; ++c)
                p[c][reg] = __builtin_amdgcn_exp2f(pacc[c][reg] + a2v[c]);
            prow[reg] = (p[0][reg] + p[1][reg]) + (p[2][reg] + p[3][reg]);
        }
#pragma unroll
        for (int reg = 0; reg < 4; ++reg) {
            float v = prow[reg];
            v += __shfl_xor(v, 1);  v += __shfl_xor(v, 2);
            v += __shfl_xor(v, 4);  v += __shfl_xor(v, 8);
            v = fmaxf(v, 1e-35f);
            ll_acc += __builtin_amdgcn_logf(v);       // log2
            inv[reg] = __builtin_amdgcn_rcpf(v);
        }

        // P -> bf16, C layout -> A layout via wave-local LDS tile
#pragma unroll
        for (int c = 0; c < 4; ++c)
#pragma unroll
            for (int reg = 0; reg < 4; ++reg)
                *(unsigned short*)(pbase + (gq * 4 + reg) * 144 + (c * 16 + gi) * 2) =
                    f2bf(p[c][reg]);

        // E = P @ MU  (K=64, 2 k-steps)
        bf16x8 ap0 = *(const bf16x8*)(pbase + gi * 144 + gq * 16);
        bf16x8 ap1 = *(const bf16x8*)(pbase + gi * 144 + 64 + gq * 16);
        f32x4 e = {0.0f, 0.0f, 0.0f, 0.0f};
        e = __builtin_amdgcn_mfma_f32_16x16x32_bf16(ap0, mf0, e, 0, 0, 0);
        e = __builtin_amdgcn_mfma_f32_16x16x32_bf16(ap1, mf1, e, 0, 0, 0);

        size_t trow = tblk + (size_t)w * 32 + rt * 16 + gq * 4;
#pragma unroll
        for (int reg = 0; reg < 4; ++reg)
            out[1 + (trow + reg) * 16 + gi] = e[reg] * inv[reg];
    }

    // ---- per-block loglike partial + last-block-done final reduce ----
    ll_acc += __shfl_xor(ll_acc, 16);
    ll_acc += __shfl_xor(ll_acc, 32);
    if (lane == 0) ((float*)(lds + L_RED))[w] = ll_acc;
    __syncthreads();
    if (tid == 0) {
        float* r = (float*)(lds + L_RED);
        float pv = (r[0] + r[1]) + (r[2] + r[3]);
        __hip_atomic_store(&part[blockIdx.x], pv, __ATOMIC_RELEASE, __HIP_MEMORY_SCOPE_AGENT);
        unsigned old = __hip_atomic_fetch_add(cnt, 1u, __ATOMIC_ACQ_REL, __HIP_MEMORY_SCOPE_AGENT);
        *(int*)(lds + L_FLAG) = (old == NBLOCKS - 1) ? 1 : 0;
    }
    __syncthreads();
    if (*(int*)(lds + L_FLAG)) {
        double s = 0.0;
#pragma unroll
        for (int k = 0; k < 8; ++k)
            s += (double)__hip_atomic_load(&part[tid + k * 256], __ATOMIC_ACQUIRE,
                                           __HIP_MEMORY_SCOPE_AGENT);
#pragma unroll
        for (int off = 32; off > 0; off >>= 1) s += __shfl_down(s, off, 64);
        if (lane == 0) ((double*)(lds + L_DRED))[w] = s;
        __syncthreads();
        if (tid == 0) {
            double* dr = (double*)(lds + L_DRED);
            const double LN2 = 0.6931471805599453;
            out[0] = (float)(((dr[0] + dr[1]) + (dr[2] + dr[3])) * LN2 / (double)T_TOTAL);
        }
    }
}

extern "C" void kernel_launch(void* const* d_in, const int* in_sizes, int n_in,
                              void* d_out, int out_size, void* d_ws, size_t ws_size,
                              hipStream_t stream) {
    const float* data  = (const float*)d_in[0];
    const float* wghts = (const float*)d_in[1];
    const float* means = (const float*)d_in[2];
    const float* dcovs = (const float*)d_in[3];
    float* out  = (float*)d_out;
    float* part = (float*)d_ws;                         // 2048 fp32 partials
    unsigned* cnt = (unsigned*)((char*)d_ws + 8192);    // ticket counter

    hipMemsetAsync(cnt, 0, 4, stream);                  // graph-capturable
    gmm_main<<<NBLOCKS, 256, 0, stream>>>(data, wghts, means, dcovs, out, part, cnt);
}

// Round 6
// 104.273 us; speedup vs baseline: 1.8197x; 1.8197x over previous
//
#include <hip/hip_runtime.h>

#define T_TOTAL 262144
#define NBLOCKS 2048
#define NMIX 64
#define NDIM 16

typedef short bf16x8 __attribute__((ext_vector_type(8)));
typedef unsigned short u16x8 __attribute__((ext_vector_type(8)));
typedef float f32x4 __attribute__((ext_vector_type(4)));

__device__ __forceinline__ unsigned short f2bf(float f) {
    union { float f; unsigned u; } v; v.f = f;
    unsigned r = v.u + 0x7fff + ((v.u >> 16) & 1);   // RNE
    return (unsigned short)(r >> 16);
}
__device__ __forceinline__ float bf2f(unsigned short s) {
    union { unsigned u; float f; } v; v.u = ((unsigned)s) << 16;
    return v.f;
}

// LDS layout (bytes):
//   L_WH  0      64 rows x 80 B (32 bf16 + pad)         5120
//   L_WL  5120                                           5120
//   L_MUT 10240  16 rows x 144 B (64 bf16 + pad)         2304
//   L_A2  12544  64 f32                                   256
//   L_RED 12800  4 f32 loglike partials                    64
//   L_F   12864  4 waves x (Fh 32x80 | Fl 32x80)        20480
//   L_P   33344  4 waves x 16 rows x 144 B               9216
//   total 42560
#define L_WH   0
#define L_WL   5120
#define L_MUT  10240
#define L_A2   12544
#define L_RED  12800
#define L_F    12864
#define L_P    33344

__global__ __launch_bounds__(256, 3) void gmm_main(const float* __restrict__ data,
                                                   const float* __restrict__ wghts,
                                                   const float* __restrict__ means,
                                                   const float* __restrict__ dcovs,
                                                   float* __restrict__ out) {
    __shared__ __align__(16) char lds[42560];
    const int tid  = threadIdx.x;
    const int w    = tid >> 6;        // wave id
    const int lane = tid & 63;
    const int gi   = lane & 15;       // fragment row/col index
    const int gq   = lane >> 4;       // fragment quad
    const size_t tblk = (size_t)blockIdx.x * 128;

    // ---- phase A: issue this thread's data loads (overlap with W prep) ----
    const int row = tid >> 1, half = tid & 1;     // local point 0..127, dim-half
    const float4* xp = (const float4*)(data + (tblk + row) * 16 + half * 8);
    float4 xa = xp[0], xb = xp[1];

    // ---- phase B: W/MU/A2 prep by wave 0 (m = tid) from raw params ----
    if (tid < 64) {
        const int m = tid;
        const float LOG2E = 1.4426950408889634f;
        const float LOG2_2PI = 2.6514961294723187f;  // log2(6.283185307)
        float dc[16], mu[16];
        {
            const float4* dp = (const float4*)(dcovs + m * 16);
            const float4* mp = (const float4*)(means + m * 16);
#pragma unroll
            for (int q = 0; q < 4; ++q) {
                float4 d4 = dp[q], m4 = mp[q];
                dc[q*4+0]=d4.x; dc[q*4+1]=d4.y; dc[q*4+2]=d4.z; dc[q*4+3]=d4.w;
                mu[q*4+0]=m4.x; mu[q*4+1]=m4.y; mu[q*4+2]=m4.z; mu[q*4+3]=m4.w;
            }
        }
        u16x8 ghv[2], glv[2], hhv[2], hlv[2];
        float sumlog = 0.0f, qsum = 0.0f;
        unsigned short* mut = (unsigned short*)(lds + L_MUT);
#pragma unroll
        for (int d = 0; d < 16; ++d) {
            float pr = 1.0f / dc[d];
            float g = -0.5f * LOG2E * pr;     // coeff of x^2
            float h = LOG2E * pr * mu[d];     // coeff of x
            unsigned short gh = f2bf(g), hh = f2bf(h);
            ghv[d >> 3][d & 7] = gh;   glv[d >> 3][d & 7] = f2bf(g - bf2f(gh));
            hhv[d >> 3][d & 7] = hh;   hlv[d >> 3][d & 7] = f2bf(h - bf2f(hh));
            mut[d * 72 + m] = f2bf(mu[d]);
            sumlog += __builtin_amdgcn_logf(dc[d]);   // log2
            qsum   += pr * mu[d] * mu[d];
        }
        char* wrh = lds + L_WH + m * 80;
        char* wrl = lds + L_WL + m * 80;
        *(u16x8*)(wrh)      = ghv[0];  *(u16x8*)(wrh + 16) = ghv[1];
        *(u16x8*)(wrh + 32) = hhv[0];  *(u16x8*)(wrh + 48) = hhv[1];
        *(u16x8*)(wrl)      = glv[0];  *(u16x8*)(wrl + 16) = glv[1];
        *(u16x8*)(wrl + 32) = hlv[0];  *(u16x8*)(wrl + 48) = hlv[1];
        float log2C = __builtin_amdgcn_logf(wghts[m]) - 8.0f * LOG2_2PI - 0.5f * sumlog;
        ((float*)(lds + L_A2))[m] = log2C - 0.5f * LOG2E * qsum;
    }

    // ---- phase C: F staging [x^2(16), x(16)] hi/lo bf16 ----
    {
        int fw = row >> 5, lr = row & 31;     // owning wave region, local row
        float xv[8] = {xa.x, xa.y, xa.z, xa.w, xb.x, xb.y, xb.z, xb.w};
        u16x8 vh2, vl2, vhx, vlx;
#pragma unroll
        for (int d = 0; d < 8; ++d) {
            float q = xv[d] * xv[d];
            unsigned short qh = f2bf(q);
            vh2[d] = qh;               vl2[d] = f2bf(q - bf2f(qh));
            unsigned short xh = f2bf(xv[d]);
            vhx[d] = xh;               vlx[d] = f2bf(xv[d] - bf2f(xh));
        }
        char* fb = lds + L_F + fw * 5120 + lr * 80;
        *(u16x8*)(fb + half * 16)        = vh2;   // k = half*8+d    (x^2 terms)
        *(u16x8*)(fb + 32 + half * 16)   = vhx;   // k = 16+half*8+d (x terms)
        char* fl = fb + 2560;
        *(u16x8*)(fl + half * 16)        = vl2;
        *(u16x8*)(fl + 32 + half * 16)   = vlx;
    }
    __syncthreads();

    // ---- preload B fragments (wave-invariant) ----
    bf16x8 bh[4], bl[4];
    float a2v[4];
#pragma unroll
    for (int c = 0; c < 4; ++c) {
        bh[c] = *(const bf16x8*)(lds + L_WH + (c * 16 + gi) * 80 + gq * 16);
        bl[c] = *(const bf16x8*)(lds + L_WL + (c * 16 + gi) * 80 + gq * 16);
        a2v[c] = ((const float*)(lds + L_A2))[c * 16 + gi];
    }
    bf16x8 mf0 = *(const bf16x8*)(lds + L_MUT + gi * 144 + gq * 16);
    bf16x8 mf1 = *(const bf16x8*)(lds + L_MUT + gi * 144 + 64 + gq * 16);

    const char* fbase = lds + L_F + w * 5120;
    char* pbase = lds + L_P + w * 2304;
    float ll_acc = 0.0f;

#pragma unroll
    for (int rt = 0; rt < 2; ++rt) {
        bf16x8 ah = *(const bf16x8*)(fbase + (rt * 16 + gi) * 80 + gq * 16);
        bf16x8 al = *(const bf16x8*)(fbase + 2560 + (rt * 16 + gi) * 80 + gq * 16);

        // S = fl*wh + fh*wl + fh*wh  (hi/lo split), 4 column tiles of 16 m
        f32x4 pacc[4];
#pragma unroll
        for (int c = 0; c < 4; ++c) {
            f32x4 a = {0.0f, 0.0f, 0.0f, 0.0f};
            a = __builtin_amdgcn_mfma_f32_16x16x32_bf16(al, bh[c], a, 0, 0, 0);
            a = __builtin_amdgcn_mfma_f32_16x16x32_bf16(ah, bl[c], a, 0, 0, 0);
            a = __builtin_amdgcn_mfma_f32_16x16x32_bf16(ah, bh[c], a, 0, 0, 0);
            pacc[c] = a;
        }

        // exp2 + row sums (C layout: row = gq*4+reg, col = c*16+gi)
        float p[4][4], prow[4], inv[4];
#pragma unroll
        for (int reg = 0; reg < 4; ++reg) {
#pragma unroll
            for (int c = 0; c < 4; ++c)
                p[c][reg] = __builtin_amdgcn_exp2f(pacc[c][reg] + a2v[c]);
            prow[reg] = (p[0][reg] + p[1][reg]) + (p[2][reg] + p[3][reg]);
        }
#pragma unroll
        for (int reg = 0; reg < 4; ++reg) {
            float v = prow[reg];
            v += __shfl_xor(v, 1);  v += __shfl_xor(v, 2);
            v += __shfl_xor(v, 4);  v += __shfl_xor(v, 8);
            v = fmaxf(v, 1e-35f);
            ll_acc += __builtin_amdgcn_logf(v);       // log2
            inv[reg] = __builtin_amdgcn_rcpf(v);
        }

        // P -> bf16, C layout -> A layout via wave-local LDS tile
#pragma unroll
        for (int c = 0; c < 4; ++c)
#pragma unroll
            for (int reg = 0; reg < 4; ++reg)
                *(unsigned short*)(pbase + (gq * 4 + reg) * 144 + (c * 16 + gi) * 2) =
                    f2bf(p[c][reg]);

        // E = P @ MU  (K=64, 2 k-steps)
        bf16x8 ap0 = *(const bf16x8*)(pbase + gi * 144 + gq * 16);
        bf16x8 ap1 = *(const bf16x8*)(pbase + gi * 144 + 64 + gq * 16);
        f32x4 e = {0.0f, 0.0f, 0.0f, 0.0f};
        e = __builtin_amdgcn_mfma_f32_16x16x32_bf16(ap0, mf0, e, 0, 0, 0);
        e = __builtin_amdgcn_mfma_f32_16x16x32_bf16(ap1, mf1, e, 0, 0, 0);

        size_t trow = tblk + (size_t)w * 32 + rt * 16 + gq * 4;
#pragma unroll
        for (int reg = 0; reg < 4; ++reg)
            out[1 + (trow + reg) * 16 + gi] = e[reg] * inv[reg];
    }

    // ---- per-block loglike partial: ONE plain fp32 atomic per block ----
    // (device-scope by default; no acquire/release fence instructions emitted.
    //  Pre-scaled by ln2/T so out[0] accumulates directly to the mean.)
    ll_acc += __shfl_xor(ll_acc, 16);
    ll_acc += __shfl_xor(ll_acc, 32);
    if (lane == 0) ((float*)(lds + L_RED))[w] = ll_acc;
    __syncthreads();
    if (tid == 0) {
        float* r = (float*)(lds + L_RED);
        const float LN2_OVER_T = 0.6931471805599453f / (float)T_TOTAL;
        float pv = ((r[0] + r[1]) + (r[2] + r[3])) * LN2_OVER_T;
        atomicAdd(&out[0], pv);
    }
}

extern "C" void kernel_launch(void* const* d_in, const int* in_sizes, int n_in,
                              void* d_out, int out_size, void* d_ws, size_t ws_size,
                              hipStream_t stream) {
    const float* data  = (const float*)d_in[0];
    const float* wghts = (const float*)d_in[1];
    const float* means = (const float*)d_in[2];
    const float* dcovs = (const float*)d_in[3];
    float* out = (float*)d_out;

    hipMemsetAsync(out, 0, 4, stream);   // zero out[0] for atomic accumulation
    gmm_main<<<NBLOCKS, 256, 0, stream>>>(data, wghts, means, dcovs, out);
}

// Round 7
// 85.370 us; speedup vs baseline: 2.2226x; 1.2214x over previous
//
#include <hip/hip_runtime.h>

#define T_TOTAL 262144
#define NBLOCKS 2048
#define NMIX 64
#define NDIM 16

typedef short bf16x8 __attribute__((ext_vector_type(8)));
typedef unsigned short u16x8 __attribute__((ext_vector_type(8)));
typedef unsigned short u16x4 __attribute__((ext_vector_type(4)));
typedef float f32x4 __attribute__((ext_vector_type(4)));

__device__ __forceinline__ unsigned short f2bf(float f) {
    union { float f; unsigned u; } v; v.f = f;
    unsigned r = v.u + 0x7fff + ((v.u >> 16) & 1);   // RNE
    return (unsigned short)(r >> 16);
}
__device__ __forceinline__ float bf2f(unsigned short s) {
    union { unsigned u; float f; } v; v.u = ((unsigned)s) << 16;
    return v.f;
}

// LDS layout (bytes) — total 40512, pads to 40960 = exactly 4 blocks/CU:
//   L_WH  0      64 rows x 80 B (32 bf16 + pad)            5120
//   L_WL  5120                                              5120
//   L_MUT 10240  16 rows x 144 B (64 bf16 + pad)            2304
//   L_A2  12544  64 f32                                      256
//   L_RED 12800  4 f32 loglike partials                       64
//   L_F   12864  4 waves x 32 rows x 144 B (Fh 64|Fl 64|pad) 18432
//   L_P   31296  4 waves x 16 rows x 144 B                   9216
#define L_WH   0
#define L_WL   5120
#define L_MUT  10240
#define L_A2   12544
#define L_RED  12800
#define L_F    12864
#define L_P    31296

__global__ __launch_bounds__(256, 4) void gmm_main(const float* __restrict__ data,
                                                   const float* __restrict__ wghts,
                                                   const float* __restrict__ means,
                                                   const float* __restrict__ dcovs,
                                                   float* __restrict__ out,
                                                   float* __restrict__ part) {
    __shared__ __align__(16) char lds[40512];
    const int tid  = threadIdx.x;
    const int w    = tid >> 6;        // wave id
    const int lane = tid & 63;
    const int gi   = lane & 15;       // fragment row/col index
    const int gq   = lane >> 4;       // fragment quad
    const size_t tblk = (size_t)blockIdx.x * 128;

    // ---- phase A: issue this thread's data loads (overlap with W prep) ----
    const int row = tid >> 1, half = tid & 1;     // local point 0..127, dim-half
    const float4* xp = (const float4*)(data + (tblk + row) * 16 + half * 8);
    float4 xa = xp[0], xb = xp[1];

    // ---- phase B: distributed W/MU/A2 prep: 4 threads per mixture ----
    {
        const int m  = tid >> 2;
        const int ql = tid & 3;       // dim-quarter
        const float LOG2E = 1.4426950408889634f;
        const float LOG2_2PI = 2.6514961294723187f;  // log2(6.283185307)
        const float4 d4 = *(const float4*)(dcovs + m * 16 + ql * 4);
        const float4 m4 = *(const float4*)(means + m * 16 + ql * 4);
        const float wm = wghts[m];
        float dc[4] = {d4.x, d4.y, d4.z, d4.w};
        float mu[4] = {m4.x, m4.y, m4.z, m4.w};
        u16x4 ghv, glv, hhv, hlv;
        float sumlog = 0.0f, qsum = 0.0f;
        unsigned short* mut = (unsigned short*)(lds + L_MUT);
#pragma unroll
        for (int j = 0; j < 4; ++j) {
            float pr = __builtin_amdgcn_rcpf(dc[j]);
            float g = -0.5f * LOG2E * pr;     // coeff of x^2
            float h = LOG2E * pr * mu[j];     // coeff of x
            unsigned short gH = f2bf(g), hH = f2bf(h);
            ghv[j] = gH;  glv[j] = f2bf(g - bf2f(gH));
            hhv[j] = hH;  hlv[j] = f2bf(h - bf2f(hH));
            mut[(ql * 4 + j) * 72 + m] = f2bf(mu[j]);
            sumlog += __builtin_amdgcn_logf(dc[j]);   // log2
            qsum   += pr * mu[j] * mu[j];
        }
        char* wrh = lds + L_WH + m * 80;
        char* wrl = lds + L_WL + m * 80;
        *(u16x4*)(wrh + ql * 8)      = ghv;
        *(u16x4*)(wrh + 32 + ql * 8) = hhv;
        *(u16x4*)(wrl + ql * 8)      = glv;
        *(u16x4*)(wrl + 32 + ql * 8) = hlv;
        sumlog += __shfl_xor(sumlog, 1); sumlog += __shfl_xor(sumlog, 2);
        qsum   += __shfl_xor(qsum, 1);   qsum   += __shfl_xor(qsum, 2);
        if (ql == 0) {
            float log2C = __builtin_amdgcn_logf(wm) - 8.0f * LOG2_2PI - 0.5f * sumlog;
            ((float*)(lds + L_A2))[m] = log2C - 0.5f * LOG2E * qsum;
        }
    }

    // ---- phase C: F staging, merged rows [Fh(64B) | Fl(64B) | pad(16B)] ----
    {
        int fw = row >> 5, lr = row & 31;     // owning wave region, local row
        float xv[8] = {xa.x, xa.y, xa.z, xa.w, xb.x, xb.y, xb.z, xb.w};
        u16x8 vh2, vl2, vhx, vlx;
#pragma unroll
        for (int d = 0; d < 8; ++d) {
            float q = xv[d] * xv[d];
            unsigned short qh = f2bf(q);
            vh2[d] = qh;               vl2[d] = f2bf(q - bf2f(qh));
            unsigned short xh = f2bf(xv[d]);
            vhx[d] = xh;               vlx[d] = f2bf(xv[d] - bf2f(xh));
        }
        char* fb = lds + L_F + fw * 4608 + lr * 144;
        *(u16x8*)(fb + half * 16)        = vh2;   // Fh: k = half*8+d    (x^2)
        *(u16x8*)(fb + 32 + half * 16)   = vhx;   // Fh: k = 16+half*8+d (x)
        *(u16x8*)(fb + 64 + half * 16)   = vl2;   // Fl
        *(u16x8*)(fb + 96 + half * 16)   = vlx;
    }
    __syncthreads();

    // ---- preload B fragments (wave-invariant) ----
    bf16x8 bh[4], bl[4];
    float a2v[4];
#pragma unroll
    for (int c = 0; c < 4; ++c) {
        bh[c] = *(const bf16x8*)(lds + L_WH + (c * 16 + gi) * 80 + gq * 16);
        bl[c] = *(const bf16x8*)(lds + L_WL + (c * 16 + gi) * 80 + gq * 16);
        a2v[c] = ((const float*)(lds + L_A2))[c * 16 + gi];
    }
    bf16x8 mf0 = *(const bf16x8*)(lds + L_MUT + gi * 144 + gq * 16);
    bf16x8 mf1 = *(const bf16x8*)(lds + L_MUT + gi * 144 + 64 + gq * 16);

    const char* fbase = lds + L_F + w * 4608;
    char* pbase = lds + L_P + w * 2304;
    float ll_acc = 0.0f;

#pragma unroll
    for (int rt = 0; rt < 2; ++rt) {
        bf16x8 ah = *(const bf16x8*)(fbase + (rt * 16 + gi) * 144 + gq * 16);
        bf16x8 al = *(const bf16x8*)(fbase + (rt * 16 + gi) * 144 + 64 + gq * 16);

        // S = fl*wh + fh*wl + fh*wh  (hi/lo split), 4 column tiles of 16 m
        f32x4 pacc[4];
#pragma unroll
        for (int c = 0; c < 4; ++c) {
            f32x4 a = {0.0f, 0.0f, 0.0f, 0.0f};
            a = __builtin_amdgcn_mfma_f32_16x16x32_bf16(al, bh[c], a, 0, 0, 0);
            a = __builtin_amdgcn_mfma_f32_16x16x32_bf16(ah, bl[c], a, 0, 0, 0);
            a = __builtin_amdgcn_mfma_f32_16x16x32_bf16(ah, bh[c], a, 0, 0, 0);
            pacc[c] = a;
        }

        // exp2 + row sums (C layout: row = gq*4+reg, col = c*16+gi)
        float p[4][4], prow[4], inv[4];
#pragma unroll
        for (int reg = 0; reg < 4; ++reg) {
#pragma unroll
            for (int c = 0; c < 4; ++c)
                p[c][reg] = __builtin_amdgcn_exp2f(pacc[c][reg] + a2v[c]);
            prow[reg] = (p[0][reg] + p[1][reg]) + (p[2][reg] + p[3][reg]);
        }
#pragma unroll
        for (int reg = 0; reg < 4; ++reg) {
            float v = prow[reg];
            v += __shfl_xor(v, 1);  v += __shfl_xor(v, 2);
            v += __shfl_xor(v, 4);  v += __shfl_xor(v, 8);
            v = fmaxf(v, 1e-35f);
            ll_acc += __builtin_amdgcn_logf(v);       // log2
            inv[reg] = __builtin_amdgcn_rcpf(v);
        }

        // P -> bf16, C layout -> A layout via wave-local LDS tile
#pragma unroll
        for (int c = 0; c < 4; ++c)
#pragma unroll
            for (int reg = 0; reg < 4; ++reg)
                *(unsigned short*)(pbase + (gq * 4 + reg) * 144 + (c * 16 + gi) * 2) =
                    f2bf(p[c][reg]);

        // E = P @ MU  (K=64, 2 k-steps)
        bf16x8 ap0 = *(const bf16x8*)(pbase + gi * 144 + gq * 16);
        bf16x8 ap1 = *(const bf16x8*)(pbase + gi * 144 + 64 + gq * 16);
        f32x4 e = {0.0f, 0.0f, 0.0f, 0.0f};
        e = __builtin_amdgcn_mfma_f32_16x16x32_bf16(ap0, mf0, e, 0, 0, 0);
        e = __builtin_amdgcn_mfma_f32_16x16x32_bf16(ap1, mf1, e, 0, 0, 0);

        size_t trow = tblk + (size_t)w * 32 + rt * 16 + gq * 4;
#pragma unroll
        for (int reg = 0; reg < 4; ++reg)
            out[1 + (trow + reg) * 16 + gi] = e[reg] * inv[reg];
    }

    // ---- per-block loglike partial: plain store to distinct address.
    //      (single-address atomics serialize ~20ns/RMW -> 41us tail at 2048
    //       blocks [R1/R2/R3/R6 evidence]; kernel-boundary L2 WB-INV makes
    //       these stores visible to gmm_fin.) ----
    ll_acc += __shfl_xor(ll_acc, 16);
    ll_acc += __shfl_xor(ll_acc, 32);
    if (lane == 0) ((float*)(lds + L_RED))[w] = ll_acc;
    __syncthreads();
    if (tid == 0) {
        float* r = (float*)(lds + L_RED);
        part[blockIdx.x] = (r[0] + r[1]) + (r[2] + r[3]);
    }
}

__global__ void gmm_fin(const float* __restrict__ part, float* __restrict__ out) {
    __shared__ double red[4];
    const int tid = threadIdx.x;
    double s = 0.0;
#pragma unroll
    for (int k = 0; k < 8; ++k) s += (double)part[tid + k * 256];
#pragma unroll
    for (int off = 32; off > 0; off >>= 1) s += __shfl_down(s, off, 64);
    const int wv = tid >> 6, lane = tid & 63;
    if (lane == 0) red[wv] = s;
    __syncthreads();
    if (tid == 0) {
        const double LN2 = 0.6931471805599453;
        double tot = (red[0] + red[1]) + (red[2] + red[3]);
        out[0] = (float)(tot * LN2 / (double)T_TOTAL);
    }
}

extern "C" void kernel_launch(void* const* d_in, const int* in_sizes, int n_in,
                              void* d_out, int out_size, void* d_ws, size_t ws_size,
                              hipStream_t stream) {
    const float* data  = (const float*)d_in[0];
    const float* wghts = (const float*)d_in[1];
    const float* means = (const float*)d_in[2];
    const float* dcovs = (const float*)d_in[3];
    float* out  = (float*)d_out;
    float* part = (float*)d_ws;   // 2048 fp32 partials (distinct addresses)

    gmm_main<<<NBLOCKS, 256, 0, stream>>>(data, wghts, means, dcovs, out, part);
    gmm_fin<<<1, 256, 0, stream>>>(part, out);
}